// Round 9
// baseline (12098.045 us; speedup 1.0000x reference)
//
#include <hip/hip_runtime.h>
#include <hip/hip_bf16.h>
#include <hip/hip_cooperative_groups.h>

namespace cg = cooperative_groups;

#define VOCAB  32000
#define EMBED  256
#define HIDDEN 1024
#define G4     4096
#define BATCH  64
#define SEQ    256

typedef short s16x8 __attribute__((ext_vector_type(8)));
typedef float f32x4 __attribute__((ext_vector_type(4)));

static __device__ __forceinline__ unsigned short f2bf(float f) {
    unsigned u = __float_as_uint(f);
    unsigned r = (u + 0x7fffu + ((u >> 16) & 1u)) >> 16;   // RNE
    return (unsigned short)r;
}
static __device__ __forceinline__ float bf2f(unsigned short s) {
    return __uint_as_float(((unsigned)s) << 16);
}

// ---------------------------------------------------------------------------
// Kernel 0: W_hh -> fragment-ready split-bf16 layout (unchanged from r8).
// Wf[tile(256)][kstep(32)][part(2)][lane(64)][e(8)] shorts, 16 MB.
// ---------------------------------------------------------------------------
__global__ __launch_bounds__(256) void lstm_wprep(
    const float* __restrict__ W_hh,        // [4096][1024]
    unsigned short* __restrict__ Wf)
{
    const int tile = blockIdx.x;           // 0..255
    const int ky   = blockIdx.y;           // 0..7
    const int tid  = threadIdx.x;
    const int wv   = tid >> 6;             // 0..3
    const int lane = tid & 63;
    const int ks   = ky * 4 + wv;          // 0..31
    const int r    = lane & 15;
    const int g    = lane >> 4;
    const int grow = (r >> 2) * 1024 + tile * 4 + (r & 3);
    const float* src = W_hh + (long)grow * 1024 + ks * 32 + g * 8;

    s16x8 hi, lo;
#pragma unroll
    for (int e = 0; e < 8; ++e) {
        const float v = src[e];
        const unsigned short h = f2bf(v);
        hi[e] = (short)h;
        lo[e] = (short)f2bf(v - bf2f(h));
    }
    s16x8* dst = (s16x8*)(Wf + ((long)(tile * 32 + ks) * 2) * 512) + lane;
    dst[0]  = hi;    // part 0
    dst[64] = lo;    // part 1 (+512 shorts)
}

// ---------------------------------------------------------------------------
// Kernel 1: xgT[t][n][b] (unchanged f32 path — keep bisectable)
// ---------------------------------------------------------------------------
__global__ __launch_bounds__(256) void lstm_xgates(
    const int* __restrict__ x,           // [B, T]
    const float* __restrict__ emb,       // [VOCAB, EMBED]
    const float* __restrict__ W_ih,      // [G4, EMBED]
    const float* __restrict__ b_ih,
    const float* __restrict__ b_hh,
    float* __restrict__ xgT)             // [T, G4, B]
{
    const int t   = blockIdx.y;
    const int n0  = blockIdx.x * 64;
    const int tid = threadIdx.x;
    const int ty  = tid >> 4;
    const int tx  = tid & 15;

    __shared__ float As[64][36];
    __shared__ float Bs[64][36];
    __shared__ int   ridx[64];

    if (tid < 64) ridx[tid] = x[tid * SEQ + t];
    __syncthreads();

    float acc[4][4];
#pragma unroll
    for (int i = 0; i < 4; ++i)
#pragma unroll
        for (int j = 0; j < 4; ++j) acc[i][j] = 0.f;

    const int lr = tid >> 2;
    const int lc = (tid & 3) * 8;
    const float* abase = W_ih + (long)(n0 + lr) * EMBED + lc;
    const float* bbase = emb + (long)ridx[lr] * EMBED + lc;

    for (int k0 = 0; k0 < EMBED; k0 += 32) {
        *(float4*)&As[lr][lc]     = *(const float4*)(abase + k0);
        *(float4*)&As[lr][lc + 4] = *(const float4*)(abase + k0 + 4);
        *(float4*)&Bs[lr][lc]     = *(const float4*)(bbase + k0);
        *(float4*)&Bs[lr][lc + 4] = *(const float4*)(bbase + k0 + 4);
        __syncthreads();

#pragma unroll
        for (int kk = 0; kk < 32; kk += 4) {
            float4 av[4], bv[4];
#pragma unroll
            for (int i = 0; i < 4; ++i) av[i] = *(const float4*)&As[ty + 16 * i][kk];
#pragma unroll
            for (int j = 0; j < 4; ++j) bv[j] = *(const float4*)&Bs[tx + 16 * j][kk];
#pragma unroll
            for (int i = 0; i < 4; ++i)
#pragma unroll
                for (int j = 0; j < 4; ++j)
                    acc[i][j] += av[i].x * bv[j].x + av[i].y * bv[j].y
                               + av[i].z * bv[j].z + av[i].w * bv[j].w;
        }
        __syncthreads();
    }

#pragma unroll
    for (int i = 0; i < 4; ++i) {
        const int n = n0 + ty + 16 * i;
        const float bias = b_ih[n] + b_hh[n];
#pragma unroll
        for (int j = 0; j < 4; ++j) {
            const int b = tx + 16 * j;
            xgT[((long)t * G4 + n) * BATCH + b] = acc[i][j] + bias;
        }
    }
}

// ---------------------------------------------------------------------------
// Kernel 2: PERSISTENT cooperative LSTM — all 256 timesteps in one launch.
//   256 blocks x 512 thr (8 waves). Block owns 16 gate-rows {g*1024+tile*4+jj}
//   x 64 b. Same MFMA split-bf16 math as r8, but:
//     - W frags loaded into registers ONCE (amortized over 256 steps)
//     - c lives in a register (never in global)
//     - h ping-pongs A<->B global bf16 hi/lo buffers, ONE grid.sync per step
//       (double-buffer makes a single sync sufficient)
//   Per-step: h frags from L2/L3, 48 MFMA/wave, Zs LDS reduce, fused gates.
// ---------------------------------------------------------------------------
__global__ __launch_bounds__(512, 2) void lstm_persist(
    const unsigned short* __restrict__ Wf,
    const float* __restrict__ xgT,       // [T][4096][64]
    unsigned short* hHiA, unsigned short* hLoA,
    unsigned short* hHiB, unsigned short* hLoB)
{
    cg::grid_group grid = cg::this_grid();

    const int tile = blockIdx.x;                                // 0..255
    const int tid  = threadIdx.x;
    const int w    = __builtin_amdgcn_readfirstlane(tid >> 6);  // 0..7
    const int lane = tid & 63;
    const int r16  = lane & 15;
    const int g    = lane >> 4;

    __shared__ float Zs[8 * 16 * 66];   // 33.8 KB split-K partials

    const s16x8* Wf8 = (const s16x8*)Wf;

    // ---- W fragments: load ONCE for all 256 timesteps ----
    s16x8 Whi[4], Wlo[4];
#pragma unroll
    for (int s = 0; s < 4; ++s) {
        const long bi = ((long)(tile * 32 + w * 4 + s) * 2) * 64 + lane;
        Whi[s] = Wf8[bi];
        Wlo[s] = Wf8[bi + 64];
    }

    // ---- h(0) = 0 (this block's slice), c in register ----
    if (w < 4) {
        hHiA[lane * HIDDEN + tile * 4 + w] = 0;
        hLoA[lane * HIDDEN + tile * 4 + w] = 0;
    }
    float creg = 0.f;

    grid.sync();   // h(0) visible everywhere

    for (int t = 0; t < SEQ; ++t) {
        const s16x8* hh8 = (const s16x8*)((t & 1) ? hHiB : hHiA);
        const s16x8* hl8 = (const s16x8*)((t & 1) ? hLoB : hLoA);
        unsigned short* ohi = (t & 1) ? hHiA : hHiB;
        unsigned short* olo = (t & 1) ? hLoA : hLoB;
        const float* xgt = xgT + (long)t * G4 * BATCH;

        // gate-phase xg operands (waves 0..3, jj=w)
        float xgv[4];
        if (w < 4) {
#pragma unroll
            for (int gg = 0; gg < 4; ++gg)
                xgv[gg] = xgt[((long)(gg << 10) + (tile << 2) + w) * BATCH + lane];
        }

        f32x4 acc[4];
#pragma unroll
        for (int m = 0; m < 4; ++m) acc[m] = (f32x4){0.f, 0.f, 0.f, 0.f};

        // h fragments, double-buffered over k-steps
        s16x8 ah[2][4], al[2][4];
#pragma unroll
        for (int m = 0; m < 4; ++m) {
            const int hidx = (m * 16 + r16) * 128 + (w * 4) * 4 + g;
            ah[0][m] = hh8[hidx];
            al[0][m] = hl8[hidx];
        }

#pragma unroll
        for (int s = 0; s < 4; ++s) {
            const int cur = s & 1, nxt = cur ^ 1;
            if (s < 3) {
#pragma unroll
                for (int m = 0; m < 4; ++m) {
                    const int hidx = (m * 16 + r16) * 128 + (w * 4 + s + 1) * 4 + g;
                    ah[nxt][m] = hh8[hidx];
                    al[nxt][m] = hl8[hidx];
                }
            }
#pragma unroll
            for (int m = 0; m < 4; ++m) {
                acc[m] = __builtin_amdgcn_mfma_f32_16x16x32_bf16(ah[cur][m], Whi[s], acc[m], 0, 0, 0);
                acc[m] = __builtin_amdgcn_mfma_f32_16x16x32_bf16(al[cur][m], Whi[s], acc[m], 0, 0, 0);
                acc[m] = __builtin_amdgcn_mfma_f32_16x16x32_bf16(ah[cur][m], Wlo[s], acc[m], 0, 0, 0);
            }
        }

        // split-K partials: D layout col=lane&15(row r16), rows of C = b
#pragma unroll
        for (int m = 0; m < 4; ++m)
#pragma unroll
            for (int q = 0; q < 4; ++q) {
                const int b = m * 16 + g * 4 + q;
                Zs[(w * 16 + r16) * 66 + b] = acc[m][q];
            }
        __syncthreads();

        // fused gate phase: wave w<4 handles jj=w, lane=b
        if (w < 4) {
            const int jj = w;
            const int b  = lane;
            float z[4];
#pragma unroll
            for (int gg = 0; gg < 4; ++gg) {
                float sum = xgv[gg];
#pragma unroll
                for (int wp = 0; wp < 8; ++wp)
                    sum += Zs[(wp * 16 + gg * 4 + jj) * 66 + b];
                z[gg] = sum;
            }
            const float ig = 1.f / (1.f + __expf(-z[0]));
            const float fg = 1.f / (1.f + __expf(-z[1]));
            const float gt = tanhf(z[2]);
            const float og = 1.f / (1.f + __expf(-z[3]));
            const float cn = fg * creg + ig * gt;
            creg = cn;
            const float hn = og * tanhf(cn);
            const unsigned short hhi = f2bf(hn);
            const unsigned short hlo = f2bf(hn - bf2f(hhi));
            ohi[b * HIDDEN + tile * 4 + jj] = hhi;
            olo[b * HIDDEN + tile * 4 + jj] = hlo;
        }

        grid.sync();   // h(t+1) visible; also fences Zs reuse
    }
}

// ---------------------------------------------------------------------------
// Kernel 3: out[b][v] = fc_b[v] + sum_k h[b][k] * fc_W[v][k]  (unchanged)
// ---------------------------------------------------------------------------
__global__ __launch_bounds__(256) void lstm_fc(
    const unsigned short* __restrict__ h_hi,   // [64][1024]
    const unsigned short* __restrict__ h_lo,
    const float* __restrict__ fc_W,            // [VOCAB, H]
    const float* __restrict__ fc_b,
    float* __restrict__ out)                   // [B, VOCAB]
{
    const int v0  = blockIdx.x * 64;
    const int tid = threadIdx.x;
    const int ty  = tid >> 4;
    const int tx  = tid & 15;

    __shared__ float Hs[64][36];
    __shared__ float Ws[64][36];

    float acc[4][4];
#pragma unroll
    for (int i = 0; i < 4; ++i)
#pragma unroll
        for (int j = 0; j < 4; ++j) acc[i][j] = 0.f;

    const int lr = tid >> 2;          // b
    const int lc = (tid & 3) * 8;     // k offset in 32-chunk
    const s16x8* hi8 = (const s16x8*)h_hi;   // [64][128]
    const s16x8* lo8 = (const s16x8*)h_lo;
    const float* wbase = fc_W + (long)(v0 + lr) * HIDDEN + lc;

    for (int k0 = 0; k0 < HIDDEN; k0 += 32) {
        const int hidx = lr * 128 + ((k0 + lc) >> 3);
        const s16x8 vh = hi8[hidx];
        const s16x8 vl = lo8[hidx];
#pragma unroll
        for (int e = 0; e < 8; ++e)
            Hs[lr][lc + e] = bf2f((unsigned short)vh[e]) + bf2f((unsigned short)vl[e]);
        *(float4*)&Ws[lr][lc]     = *(const float4*)(wbase + k0);
        *(float4*)&Ws[lr][lc + 4] = *(const float4*)(wbase + k0 + 4);
        __syncthreads();

#pragma unroll
        for (int kk = 0; kk < 32; kk += 4) {
            float4 hv[4], wv[4];
#pragma unroll
            for (int i = 0; i < 4; ++i) hv[i] = *(const float4*)&Hs[ty + 16 * i][kk];
#pragma unroll
            for (int j = 0; j < 4; ++j) wv[j] = *(const float4*)&Ws[tx + 16 * j][kk];
#pragma unroll
            for (int i = 0; i < 4; ++i)
#pragma unroll
                for (int j = 0; j < 4; ++j)
                    acc[i][j] += hv[i].x * wv[j].x + hv[i].y * wv[j].y
                               + hv[i].z * wv[j].z + hv[i].w * wv[j].w;
        }
        __syncthreads();
    }

#pragma unroll
    for (int j = 0; j < 4; ++j) {
        const int v = v0 + tx + 16 * j;
        const float bias = fc_b[v];
#pragma unroll
        for (int i = 0; i < 4; ++i) {
            const int b = ty + 16 * i;
            out[(long)b * VOCAB + v] = acc[i][j] + bias;
        }
    }
}

// ---------------------------------------------------------------------------
extern "C" void kernel_launch(void* const* d_in, const int* in_sizes, int n_in,
                              void* d_out, int out_size, void* d_ws, size_t ws_size,
                              hipStream_t stream)
{
    const int*   x     = (const int*)d_in[0];
    const float* emb   = (const float*)d_in[1];
    const float* W_ih  = (const float*)d_in[2];
    const float* W_hh  = (const float*)d_in[3];
    const float* b_ih  = (const float*)d_in[4];
    const float* b_hh  = (const float*)d_in[5];
    const float* fc_W  = (const float*)d_in[6];
    const float* fc_b  = (const float*)d_in[7];
    float* out = (float*)d_out;

    // ws layout: xgT f32 [T][4H][B] (268 MB) | Wf u16 (16 MB)
    //          | hHiA hLoA hHiB hLoB u16 (4x128 KB)
    float* xgT = (float*)d_ws;
    unsigned short* Wf   = (unsigned short*)(xgT + (long)SEQ * G4 * BATCH);
    unsigned short* hHiA = Wf + (long)256 * 32 * 2 * 512;
    unsigned short* hLoA = hHiA + BATCH * HIDDEN;
    unsigned short* hHiB = hLoA + BATCH * HIDDEN;
    unsigned short* hLoB = hHiB + BATCH * HIDDEN;

    lstm_wprep<<<dim3(256, 8), 256, 0, stream>>>(W_hh, Wf);
    lstm_xgates<<<dim3(G4 / 64, SEQ), 256, 0, stream>>>(x, emb, W_ih, b_ih, b_hh, xgT);

    void* args[] = {(void*)&Wf, (void*)&xgT,
                    (void*)&hHiA, (void*)&hLoA, (void*)&hHiB, (void*)&hLoB};
    hipLaunchCooperativeKernel((void*)lstm_persist, dim3(256), dim3(512),
                               args, 0, stream);

    // SEQ even -> final h in A buffers
    lstm_fc<<<dim3(VOCAB / 64), 256, 0, stream>>>(hHiA, hLoA, fc_W, fc_b, out);
}

// Round 10
// 11431.683 us; speedup vs baseline: 1.0583x; 1.0583x over previous
//
#include <hip/hip_runtime.h>
#include <hip/hip_bf16.h>

#define VOCAB  32000
#define EMBED  256
#define HIDDEN 1024
#define G4     4096
#define BATCH  64
#define SEQ    256

typedef short s16x8 __attribute__((ext_vector_type(8)));
typedef float f32x4 __attribute__((ext_vector_type(4)));
typedef unsigned long long u64;

static __device__ __forceinline__ unsigned short f2bf(float f) {
    unsigned u = __float_as_uint(f);
    unsigned r = (u + 0x7fffu + ((u >> 16) & 1u)) >> 16;   // RNE
    return (unsigned short)r;
}
static __device__ __forceinline__ float bf2f(unsigned short s) {
    return __uint_as_float(((unsigned)s) << 16);
}
static __device__ __forceinline__ s16x8 mkfrag(u64 q0, u64 q1) {
    s16x8 r;
    ((u64*)&r)[0] = q0;
    ((u64*)&r)[1] = q1;
    return r;
}

// ---------------------------------------------------------------------------
// Kernel 0: W_hh -> fragment-ready split-bf16 layout (unchanged from r8).
// Wf[tile(256)][kstep(32)][part(2)][lane(64)][e(8)] shorts, 16 MB.
// ---------------------------------------------------------------------------
__global__ __launch_bounds__(256) void lstm_wprep(
    const float* __restrict__ W_hh,        // [4096][1024]
    unsigned short* __restrict__ Wf)
{
    const int tile = blockIdx.x;           // 0..255
    const int ky   = blockIdx.y;           // 0..7
    const int tid  = threadIdx.x;
    const int wv   = tid >> 6;             // 0..3
    const int lane = tid & 63;
    const int ks   = ky * 4 + wv;          // 0..31
    const int r    = lane & 15;
    const int g    = lane >> 4;
    const int grow = (r >> 2) * 1024 + tile * 4 + (r & 3);
    const float* src = W_hh + (long)grow * 1024 + ks * 32 + g * 8;

    s16x8 hi, lo;
#pragma unroll
    for (int e = 0; e < 8; ++e) {
        const float v = src[e];
        const unsigned short h = f2bf(v);
        hi[e] = (short)h;
        lo[e] = (short)f2bf(v - bf2f(h));
    }
    s16x8* dst = (s16x8*)(Wf + ((long)(tile * 32 + ks) * 2) * 512) + lane;
    dst[0]  = hi;    // part 0
    dst[64] = lo;    // part 1 (+512 shorts)
}

// ---------------------------------------------------------------------------
// Kernel 1: xgT[t][n][b] (unchanged f32 path — keep bisectable)
// ---------------------------------------------------------------------------
__global__ __launch_bounds__(256) void lstm_xgates(
    const int* __restrict__ x,           // [B, T]
    const float* __restrict__ emb,       // [VOCAB, EMBED]
    const float* __restrict__ W_ih,      // [G4, EMBED]
    const float* __restrict__ b_ih,
    const float* __restrict__ b_hh,
    float* __restrict__ xgT)             // [T, G4, B]
{
    const int t   = blockIdx.y;
    const int n0  = blockIdx.x * 64;
    const int tid = threadIdx.x;
    const int ty  = tid >> 4;
    const int tx  = tid & 15;

    __shared__ float As[64][36];
    __shared__ float Bs[64][36];
    __shared__ int   ridx[64];

    if (tid < 64) ridx[tid] = x[tid * SEQ + t];
    __syncthreads();

    float acc[4][4];
#pragma unroll
    for (int i = 0; i < 4; ++i)
#pragma unroll
        for (int j = 0; j < 4; ++j) acc[i][j] = 0.f;

    const int lr = tid >> 2;
    const int lc = (tid & 3) * 8;
    const float* abase = W_ih + (long)(n0 + lr) * EMBED + lc;
    const float* bbase = emb + (long)ridx[lr] * EMBED + lc;

    for (int k0 = 0; k0 < EMBED; k0 += 32) {
        *(float4*)&As[lr][lc]     = *(const float4*)(abase + k0);
        *(float4*)&As[lr][lc + 4] = *(const float4*)(abase + k0 + 4);
        *(float4*)&Bs[lr][lc]     = *(const float4*)(bbase + k0);
        *(float4*)&Bs[lr][lc + 4] = *(const float4*)(bbase + k0 + 4);
        __syncthreads();

#pragma unroll
        for (int kk = 0; kk < 32; kk += 4) {
            float4 av[4], bv[4];
#pragma unroll
            for (int i = 0; i < 4; ++i) av[i] = *(const float4*)&As[ty + 16 * i][kk];
#pragma unroll
            for (int j = 0; j < 4; ++j) bv[j] = *(const float4*)&Bs[tx + 16 * j][kk];
#pragma unroll
            for (int i = 0; i < 4; ++i)
#pragma unroll
                for (int j = 0; j < 4; ++j)
                    acc[i][j] += av[i].x * bv[j].x + av[i].y * bv[j].y
                               + av[i].z * bv[j].z + av[i].w * bv[j].w;
        }
        __syncthreads();
    }

#pragma unroll
    for (int i = 0; i < 4; ++i) {
        const int n = n0 + ty + 16 * i;
        const float bias = b_ih[n] + b_hh[n];
#pragma unroll
        for (int j = 0; j < 4; ++j) {
            const int b = tx + 16 * j;
            xgT[((long)t * G4 + n) * BATCH + b] = acc[i][j] + bias;
        }
    }
}

// ---------------------------------------------------------------------------
// Zero h(0) planes (A) and the barrier cells. (ws poisoned 0xAA each call.)
// ---------------------------------------------------------------------------
__global__ void lstm_init(unsigned* __restrict__ hhi,
                          unsigned* __restrict__ hlo,
                          unsigned* __restrict__ bar)
{
    const int i = blockIdx.x * blockDim.x + threadIdx.x;
    if (i < BATCH * 512) { hhi[i] = 0; hlo[i] = 0; }
    if (i < 2) bar[i] = 0;
}

// ---------------------------------------------------------------------------
// Kernel 2: PERSISTENT LSTM, hand-rolled epoch barrier (NO grid.sync).
//   256 blocks x 512 thr, cooperative launch (co-residency) -> 1 block/CU.
//   Cross-XCD h exchange via AGENT-scope relaxed atomics (sc1 path, no L2
//   flush). Barrier: fetch_add(ACQ_REL) + single-flag spin, 1/step.
//   Same MFMA split-bf16 math as r8 (verified, absmax 1.95e-3):
//   block owns 16 gate-rows x 64 b; 8-way split-K; all 32 h frags loaded
//   up-front (ILP hides IF$ latency); W frags + c in registers for all 256
//   steps. h planes: u32 = (bf16 hi_j, hi_j+1) pairs -> byte layout
//   identical to u16 [64][1024] (fc reads them directly).
// ---------------------------------------------------------------------------
__global__ __launch_bounds__(512, 1) void lstm_persist(
    const unsigned short* __restrict__ Wf,
    const float* __restrict__ xgT,       // [T][4096][64]
    unsigned* hAhi, unsigned* hAlo,      // [64][512] u32 planes
    unsigned* hBhi, unsigned* hBlo,
    unsigned* bar)                       // bar[0]=cnt, bar[1]=flag
{
    const int tile = blockIdx.x;                                // 0..255
    const int tid  = threadIdx.x;
    const int w    = __builtin_amdgcn_readfirstlane(tid >> 6);  // 0..7
    const int lane = tid & 63;
    const int r16  = lane & 15;
    const int g    = lane >> 4;

    __shared__ float Zs[8 * 16 * 66];   // 33.8 KB split-K partials

    const s16x8* Wf8 = (const s16x8*)Wf;

    // ---- W fragments: load ONCE for all 256 timesteps ----
    s16x8 Whi[4], Wlo[4];
#pragma unroll
    for (int s = 0; s < 4; ++s) {
        const long bi = ((long)(tile * 32 + w * 4 + s) * 2) * 64 + lane;
        Whi[s] = Wf8[bi];
        Wlo[s] = Wf8[bi + 64];
    }

    float creg[2] = {0.f, 0.f};   // c for (b=lane, jj=2w+jjj), waves 0..1

#pragma unroll 1
    for (int t = 0; t < SEQ; ++t) {
        const u64* hh8 = (const u64*)((t & 1) ? hBhi : hAhi);
        const u64* hl8 = (const u64*)((t & 1) ? hBlo : hAlo);
        unsigned* ohi = (t & 1) ? hAhi : hBhi;
        unsigned* olo = (t & 1) ? hAlo : hBlo;
        const float* xgt = xgT + (long)t * G4 * BATCH;

        // gate-phase xg operands (waves 0..1 handle jj = 2w+jjj), issue early
        float xgv[2][4];
        if (w < 2) {
#pragma unroll
            for (int jjj = 0; jjj < 2; ++jjj)
#pragma unroll
                for (int gg = 0; gg < 4; ++gg)
                    xgv[jjj][gg] = xgt[((long)(gg << 10) + (tile << 2) + 2 * w + jjj) * BATCH + lane];
        }

        // ---- load ALL h fragments up-front (device-scope, bypass stale L2) ----
        s16x8 ah[4][4], al[4][4];
#pragma unroll
        for (int m = 0; m < 4; ++m)
#pragma unroll
            for (int s = 0; s < 4; ++s) {
                const int qi = ((m * 16 + r16) << 8) + (w * 4 + s) * 8 + (g << 1);
                const u64 q0 = __hip_atomic_load(&hh8[qi],     __ATOMIC_RELAXED, __HIP_MEMORY_SCOPE_AGENT);
                const u64 q1 = __hip_atomic_load(&hh8[qi + 1], __ATOMIC_RELAXED, __HIP_MEMORY_SCOPE_AGENT);
                const u64 p0 = __hip_atomic_load(&hl8[qi],     __ATOMIC_RELAXED, __HIP_MEMORY_SCOPE_AGENT);
                const u64 p1 = __hip_atomic_load(&hl8[qi + 1], __ATOMIC_RELAXED, __HIP_MEMORY_SCOPE_AGENT);
                ah[m][s] = mkfrag(q0, q1);
                al[m][s] = mkfrag(p0, p1);
            }

        f32x4 acc[4];
#pragma unroll
        for (int m = 0; m < 4; ++m) acc[m] = (f32x4){0.f, 0.f, 0.f, 0.f};

#pragma unroll
        for (int s = 0; s < 4; ++s)
#pragma unroll
            for (int m = 0; m < 4; ++m) {
                acc[m] = __builtin_amdgcn_mfma_f32_16x16x32_bf16(ah[m][s], Whi[s], acc[m], 0, 0, 0);
                acc[m] = __builtin_amdgcn_mfma_f32_16x16x32_bf16(al[m][s], Whi[s], acc[m], 0, 0, 0);
                acc[m] = __builtin_amdgcn_mfma_f32_16x16x32_bf16(ah[m][s], Wlo[s], acc[m], 0, 0, 0);
            }

        // ---- split-K partials ----
#pragma unroll
        for (int m = 0; m < 4; ++m)
#pragma unroll
            for (int q = 0; q < 4; ++q) {
                const int b = m * 16 + g * 4 + q;
                Zs[(w * 16 + r16) * 66 + b] = acc[m][q];
            }
        __syncthreads();   // (A) Zs ready

        // ---- fused gate phase: wave w<2 handles jj = 2w, 2w+1; lane = b ----
        if (w < 2) {
            const int b = lane;
            unsigned short hi16[2], lo16[2];
#pragma unroll
            for (int jjj = 0; jjj < 2; ++jjj) {
                const int jj = 2 * w + jjj;
                float z[4];
#pragma unroll
                for (int gg = 0; gg < 4; ++gg) {
                    float sum = xgv[jjj][gg];
#pragma unroll
                    for (int wp = 0; wp < 8; ++wp)
                        sum += Zs[(wp * 16 + gg * 4 + jj) * 66 + b];
                    z[gg] = sum;
                }
                const float ig = 1.f / (1.f + __expf(-z[0]));
                const float fg = 1.f / (1.f + __expf(-z[1]));
                const float gt = tanhf(z[2]);
                const float og = 1.f / (1.f + __expf(-z[3]));
                const float cn = fg * creg[jjj] + ig * gt;
                creg[jjj] = cn;
                const float hn = og * tanhf(cn);
                hi16[jjj] = f2bf(hn);
                lo16[jjj] = f2bf(hn - bf2f(hi16[jjj]));
            }
            const unsigned hiw = (unsigned)hi16[0] | ((unsigned)hi16[1] << 16);
            const unsigned low = (unsigned)lo16[0] | ((unsigned)lo16[1] << 16);
            const int pidx = b * 512 + tile * 2 + w;
            __hip_atomic_store(&ohi[pidx], hiw, __ATOMIC_RELAXED, __HIP_MEMORY_SCOPE_AGENT);
            __hip_atomic_store(&olo[pidx], low, __ATOMIC_RELAXED, __HIP_MEMORY_SCOPE_AGENT);
        }
        __syncthreads();   // (B) every thread's stores drained (vmcnt 0)

        // ---- device-wide epoch barrier (skip after the final step) ----
        if (t < SEQ - 1) {
            if (tid == 0) {
                const unsigned epoch  = (unsigned)(t + 1);
                const unsigned target = 256u * epoch;
                const unsigned arr = __hip_atomic_fetch_add(&bar[0], 1u,
                                        __ATOMIC_ACQ_REL, __HIP_MEMORY_SCOPE_AGENT);
                if (arr == target - 1u) {
                    __hip_atomic_store(&bar[1], epoch,
                                       __ATOMIC_RELEASE, __HIP_MEMORY_SCOPE_AGENT);
                } else {
                    while (__hip_atomic_load(&bar[1], __ATOMIC_ACQUIRE,
                                             __HIP_MEMORY_SCOPE_AGENT) < epoch)
                        __builtin_amdgcn_s_sleep(1);
                }
            }
            __syncthreads();   // (C) whole block released
        }
    }
}

// ---------------------------------------------------------------------------
// Kernel 3: out[b][v] = fc_b[v] + sum_k h[b][k] * fc_W[v][k]  (unchanged;
// the u32 planes have the same byte layout as u16 [64][1024])
// ---------------------------------------------------------------------------
__global__ __launch_bounds__(256) void lstm_fc(
    const unsigned short* __restrict__ h_hi,   // [64][1024]
    const unsigned short* __restrict__ h_lo,
    const float* __restrict__ fc_W,            // [VOCAB, H]
    const float* __restrict__ fc_b,
    float* __restrict__ out)                   // [B, VOCAB]
{
    const int v0  = blockIdx.x * 64;
    const int tid = threadIdx.x;
    const int ty  = tid >> 4;
    const int tx  = tid & 15;

    __shared__ float Hs[64][36];
    __shared__ float Ws[64][36];

    float acc[4][4];
#pragma unroll
    for (int i = 0; i < 4; ++i)
#pragma unroll
        for (int j = 0; j < 4; ++j) acc[i][j] = 0.f;

    const int lr = tid >> 2;          // b
    const int lc = (tid & 3) * 8;     // k offset in 32-chunk
    const s16x8* hi8 = (const s16x8*)h_hi;   // [64][128]
    const s16x8* lo8 = (const s16x8*)h_lo;
    const float* wbase = fc_W + (long)(v0 + lr) * HIDDEN + lc;

    for (int k0 = 0; k0 < HIDDEN; k0 += 32) {
        const int hidx = lr * 128 + ((k0 + lc) >> 3);
        const s16x8 vh = hi8[hidx];
        const s16x8 vl = lo8[hidx];
#pragma unroll
        for (int e = 0; e < 8; ++e)
            Hs[lr][lc + e] = bf2f((unsigned short)vh[e]) + bf2f((unsigned short)vl[e]);
        *(float4*)&Ws[lr][lc]     = *(const float4*)(wbase + k0);
        *(float4*)&Ws[lr][lc + 4] = *(const float4*)(wbase + k0 + 4);
        __syncthreads();

#pragma unroll
        for (int kk = 0; kk < 32; kk += 4) {
            float4 hv[4], wv[4];
#pragma unroll
            for (int i = 0; i < 4; ++i) hv[i] = *(const float4*)&Hs[ty + 16 * i][kk];
#pragma unroll
            for (int j = 0; j < 4; ++j) wv[j] = *(const float4*)&Ws[tx + 16 * j][kk];
#pragma unroll
            for (int i = 0; i < 4; ++i)
#pragma unroll
                for (int j = 0; j < 4; ++j)
                    acc[i][j] += hv[i].x * wv[j].x + hv[i].y * wv[j].y
                               + hv[i].z * wv[j].z + hv[i].w * wv[j].w;
        }
        __syncthreads();
    }

#pragma unroll
    for (int j = 0; j < 4; ++j) {
        const int v = v0 + tx + 16 * j;
        const float bias = fc_b[v];
#pragma unroll
        for (int i = 0; i < 4; ++i) {
            const int b = ty + 16 * i;
            out[(long)b * VOCAB + v] = acc[i][j] + bias;
        }
    }
}

// ---------------------------------------------------------------------------
extern "C" void kernel_launch(void* const* d_in, const int* in_sizes, int n_in,
                              void* d_out, int out_size, void* d_ws, size_t ws_size,
                              hipStream_t stream)
{
    const int*   x     = (const int*)d_in[0];
    const float* emb   = (const float*)d_in[1];
    const float* W_ih  = (const float*)d_in[2];
    const float* W_hh  = (const float*)d_in[3];
    const float* b_ih  = (const float*)d_in[4];
    const float* b_hh  = (const float*)d_in[5];
    const float* fc_W  = (const float*)d_in[6];
    const float* fc_b  = (const float*)d_in[7];
    float* out = (float*)d_out;

    // ws layout: xgT f32 [T][4H][B] (268 MB) | Wf u16 (16 MB)
    //          | hAhi hAlo hBhi hBlo u32 planes (4x128 KB) | bar (2 u32)
    float* xgT = (float*)d_ws;
    unsigned short* Wf = (unsigned short*)(xgT + (long)SEQ * G4 * BATCH);
    unsigned* hAhi = (unsigned*)(Wf + (long)256 * 32 * 2 * 512);
    unsigned* hAlo = hAhi + BATCH * 512;
    unsigned* hBhi = hAlo + BATCH * 512;
    unsigned* hBlo = hBhi + BATCH * 512;
    unsigned* bar  = hBlo + BATCH * 512;

    lstm_wprep<<<dim3(256, 8), 256, 0, stream>>>(W_hh, Wf);
    lstm_xgates<<<dim3(G4 / 64, SEQ), 256, 0, stream>>>(x, emb, W_ih, b_ih, b_hh, xgT);
    lstm_init<<<dim3(BATCH * 512 / 256), 256, 0, stream>>>(hAhi, hAlo, bar);

    void* args[] = {(void*)&Wf, (void*)&xgT,
                    (void*)&hAhi, (void*)&hAlo, (void*)&hBhi, (void*)&hBlo,
                    (void*)&bar};
    hipLaunchCooperativeKernel((void*)lstm_persist, dim3(256), dim3(512),
                               args, 0, stream);

    // SEQ even -> final h in A planes
    lstm_fc<<<dim3(VOCAB / 64), 256, 0, stream>>>(
        (const unsigned short*)hAhi, (const unsigned short*)hAlo, fc_W, fc_b, out);
}

// Round 11
// 3416.571 us; speedup vs baseline: 3.5410x; 3.3460x over previous
//
#include <hip/hip_runtime.h>
#include <hip/hip_bf16.h>

#define VOCAB  32000
#define EMBED  256
#define HIDDEN 1024
#define G4     4096
#define BATCH  64
#define SEQ    256

typedef short s16x8 __attribute__((ext_vector_type(8)));
typedef float f32x4 __attribute__((ext_vector_type(4)));
typedef unsigned long long u64;

static __device__ __forceinline__ unsigned short f2bf(float f) {
    unsigned u = __float_as_uint(f);
    unsigned r = (u + 0x7fffu + ((u >> 16) & 1u)) >> 16;   // RNE
    return (unsigned short)r;
}
static __device__ __forceinline__ float bf2f(unsigned short s) {
    return __uint_as_float(((unsigned)s) << 16);
}
static __device__ __forceinline__ s16x8 mkfrag(u64 q0, u64 q1) {
    s16x8 r;
    ((u64*)&r)[0] = q0;
    ((u64*)&r)[1] = q1;
    return r;
}

// ---------------------------------------------------------------------------
// Kernel 0: W_hh -> fragment-ready split-bf16 layout (unchanged, verified).
// ---------------------------------------------------------------------------
__global__ __launch_bounds__(256) void lstm_wprep(
    const float* __restrict__ W_hh,        // [4096][1024]
    unsigned short* __restrict__ Wf)
{
    const int tile = blockIdx.x;           // 0..255
    const int ky   = blockIdx.y;           // 0..7
    const int tid  = threadIdx.x;
    const int wv   = tid >> 6;             // 0..3
    const int lane = tid & 63;
    const int ks   = ky * 4 + wv;          // 0..31
    const int r    = lane & 15;
    const int g    = lane >> 4;
    const int grow = (r >> 2) * 1024 + tile * 4 + (r & 3);
    const float* src = W_hh + (long)grow * 1024 + ks * 32 + g * 8;

    s16x8 hi, lo;
#pragma unroll
    for (int e = 0; e < 8; ++e) {
        const float v = src[e];
        const unsigned short h = f2bf(v);
        hi[e] = (short)h;
        lo[e] = (short)f2bf(v - bf2f(h));
    }
    s16x8* dst = (s16x8*)(Wf + ((long)(tile * 32 + ks) * 2) * 512) + lane;
    dst[0]  = hi;    // part 0
    dst[64] = lo;    // part 1 (+512 shorts)
}

// ---------------------------------------------------------------------------
// Kernel 1: xgT[t][n][b] (unchanged f32 path — keep bisectable)
// ---------------------------------------------------------------------------
__global__ __launch_bounds__(256) void lstm_xgates(
    const int* __restrict__ x,           // [B, T]
    const float* __restrict__ emb,       // [VOCAB, EMBED]
    const float* __restrict__ W_ih,      // [G4, EMBED]
    const float* __restrict__ b_ih,
    const float* __restrict__ b_hh,
    float* __restrict__ xgT)             // [T, G4, B]
{
    const int t   = blockIdx.y;
    const int n0  = blockIdx.x * 64;
    const int tid = threadIdx.x;
    const int ty  = tid >> 4;
    const int tx  = tid & 15;

    __shared__ float As[64][36];
    __shared__ float Bs[64][36];
    __shared__ int   ridx[64];

    if (tid < 64) ridx[tid] = x[tid * SEQ + t];
    __syncthreads();

    float acc[4][4];
#pragma unroll
    for (int i = 0; i < 4; ++i)
#pragma unroll
        for (int j = 0; j < 4; ++j) acc[i][j] = 0.f;

    const int lr = tid >> 2;
    const int lc = (tid & 3) * 8;
    const float* abase = W_ih + (long)(n0 + lr) * EMBED + lc;
    const float* bbase = emb + (long)ridx[lr] * EMBED + lc;

    for (int k0 = 0; k0 < EMBED; k0 += 32) {
        *(float4*)&As[lr][lc]     = *(const float4*)(abase + k0);
        *(float4*)&As[lr][lc + 4] = *(const float4*)(abase + k0 + 4);
        *(float4*)&Bs[lr][lc]     = *(const float4*)(bbase + k0);
        *(float4*)&Bs[lr][lc + 4] = *(const float4*)(bbase + k0 + 4);
        __syncthreads();

#pragma unroll
        for (int kk = 0; kk < 32; kk += 4) {
            float4 av[4], bv[4];
#pragma unroll
            for (int i = 0; i < 4; ++i) av[i] = *(const float4*)&As[ty + 16 * i][kk];
#pragma unroll
            for (int j = 0; j < 4; ++j) bv[j] = *(const float4*)&Bs[tx + 16 * j][kk];
#pragma unroll
            for (int i = 0; i < 4; ++i)
#pragma unroll
                for (int j = 0; j < 4; ++j)
                    acc[i][j] += av[i].x * bv[j].x + av[i].y * bv[j].y
                               + av[i].z * bv[j].z + av[i].w * bv[j].w;
        }
        __syncthreads();
    }

#pragma unroll
    for (int i = 0; i < 4; ++i) {
        const int n = n0 + ty + 16 * i;
        const float bias = b_ih[n] + b_hh[n];
#pragma unroll
        for (int j = 0; j < 4; ++j) {
            const int b = tx + 16 * j;
            xgT[((long)t * G4 + n) * BATCH + b] = acc[i][j] + bias;
        }
    }
}

// ---------------------------------------------------------------------------
// Zero h(0) planes (A) and barrier cells. (ws poisoned 0xAA each call.)
// ---------------------------------------------------------------------------
__global__ void lstm_init(unsigned* __restrict__ hhi,
                          unsigned* __restrict__ hlo,
                          unsigned* __restrict__ bar)
{
    const int i = blockIdx.x * blockDim.x + threadIdx.x;
    if (i < BATCH * 512) { hhi[i] = 0; hlo[i] = 0; }
    if (i < 2) bar[i] = 0;
}

// ---------------------------------------------------------------------------
// Kernel 2: PERSISTENT LSTM — fully RELAXED coherence (no wbL2/inv anywhere).
//   All cross-block h traffic: sc1 relaxed atomics via the IF$ coherence
//   point (proven correct in r10). Barrier: relaxed fetch_add + relaxed
//   spin; ordering = __syncthreads' vmcnt(0) drain before the add, and the
//   sc1 data path after it. h planes re-laid as [k/4][b] u64 cells so frag
//   loads coalesce in 16-lane 128B runs (r10 was 2KB-strided).
//   Math unchanged from r8/r10 (absmax 1.95e-3): 16 gate-rows x 64 b per
//   block, 8-way split-K, 48 MFMA/wave, Zs reduce, fused gates (2 waves x
//   2 j), W frags + c in registers for all 256 steps.
// ---------------------------------------------------------------------------
__global__ __launch_bounds__(512, 1) void lstm_persist(
    const unsigned short* __restrict__ Wf,
    const float* __restrict__ xgT,       // [T][4096][64]
    unsigned* hAhi, unsigned* hAlo,      // [256 kgroups][64 b] u64 cells
    unsigned* hBhi, unsigned* hBlo,
    unsigned* bar)                       // bar[0]=cnt, bar[1]=flag
{
    const int tile = blockIdx.x;                                // 0..255
    const int tid  = threadIdx.x;
    const int w    = __builtin_amdgcn_readfirstlane(tid >> 6);  // 0..7
    const int lane = tid & 63;
    const int r16  = lane & 15;
    const int g    = lane >> 4;

    __shared__ float Zs[8 * 16 * 66];   // 33.8 KB split-K partials

    const s16x8* Wf8 = (const s16x8*)Wf;

    // ---- W fragments: load ONCE for all 256 timesteps ----
    s16x8 Whi[4], Wlo[4];
#pragma unroll
    for (int s = 0; s < 4; ++s) {
        const long bi = ((long)(tile * 32 + w * 4 + s) * 2) * 64 + lane;
        Whi[s] = Wf8[bi];
        Wlo[s] = Wf8[bi + 64];
    }

    float creg[2] = {0.f, 0.f};   // c for (b=lane, jj=2w+jjj), waves 0..1

#pragma unroll 1
    for (int t = 0; t < SEQ; ++t) {
        const u64* hh8 = (const u64*)((t & 1) ? hBhi : hAhi);
        const u64* hl8 = (const u64*)((t & 1) ? hBlo : hAlo);
        unsigned* ohi = (t & 1) ? hAhi : hBhi;
        unsigned* olo = (t & 1) ? hAlo : hBlo;
        const float* xgt = xgT + (long)t * G4 * BATCH;

        // gate-phase xg operands (waves 0..1 handle jj = 2w+jjj), issue early
        float xgv[2][4];
        if (w < 2) {
#pragma unroll
            for (int jjj = 0; jjj < 2; ++jjj)
#pragma unroll
                for (int gg = 0; gg < 4; ++gg)
                    xgv[jjj][gg] = xgt[((long)(gg << 10) + (tile << 2) + 2 * w + jjj) * BATCH + lane];
        }

        // ---- load ALL h fragments up-front (sc1 path, coalesced 128B runs) ----
        // frag (m,s): rows b=m*16+r16, k0=(w*4+s)*32+g*8 -> u64 cell
        // [kg = (w*4+s)*8 + g*2][b], next 4 k at cell+64.
        s16x8 ah[4][4], al[4][4];
#pragma unroll
        for (int m = 0; m < 4; ++m)
#pragma unroll
            for (int s = 0; s < 4; ++s) {
                const int qi = ((w * 4 + s) * 8 + g * 2) * 64 + m * 16 + r16;
                const u64 q0 = __hip_atomic_load(&hh8[qi],      __ATOMIC_RELAXED, __HIP_MEMORY_SCOPE_AGENT);
                const u64 q1 = __hip_atomic_load(&hh8[qi + 64], __ATOMIC_RELAXED, __HIP_MEMORY_SCOPE_AGENT);
                const u64 p0 = __hip_atomic_load(&hl8[qi],      __ATOMIC_RELAXED, __HIP_MEMORY_SCOPE_AGENT);
                const u64 p1 = __hip_atomic_load(&hl8[qi + 64], __ATOMIC_RELAXED, __HIP_MEMORY_SCOPE_AGENT);
                ah[m][s] = mkfrag(q0, q1);
                al[m][s] = mkfrag(p0, p1);
            }

        f32x4 acc[4];
#pragma unroll
        for (int m = 0; m < 4; ++m) acc[m] = (f32x4){0.f, 0.f, 0.f, 0.f};

#pragma unroll
        for (int s = 0; s < 4; ++s)
#pragma unroll
            for (int m = 0; m < 4; ++m) {
                acc[m] = __builtin_amdgcn_mfma_f32_16x16x32_bf16(ah[m][s], Whi[s], acc[m], 0, 0, 0);
                acc[m] = __builtin_amdgcn_mfma_f32_16x16x32_bf16(al[m][s], Whi[s], acc[m], 0, 0, 0);
                acc[m] = __builtin_amdgcn_mfma_f32_16x16x32_bf16(ah[m][s], Wlo[s], acc[m], 0, 0, 0);
            }

        // ---- split-K partials ----
#pragma unroll
        for (int m = 0; m < 4; ++m)
#pragma unroll
            for (int q = 0; q < 4; ++q) {
                const int b = m * 16 + g * 4 + q;
                Zs[(w * 16 + r16) * 66 + b] = acc[m][q];
            }
        __syncthreads();   // (A) Zs ready

        // ---- fused gate phase: wave w<2 handles jj = 2w, 2w+1; lane = b ----
        if (w < 2) {
            const int b = lane;
            unsigned short hi16[2], lo16[2];
#pragma unroll
            for (int jjj = 0; jjj < 2; ++jjj) {
                const int jj = 2 * w + jjj;
                float z[4];
#pragma unroll
                for (int gg = 0; gg < 4; ++gg) {
                    float sum = xgv[jjj][gg];
#pragma unroll
                    for (int wp = 0; wp < 8; ++wp)
                        sum += Zs[(wp * 16 + gg * 4 + jj) * 66 + b];
                    z[gg] = sum;
                }
                const float ig = 1.f / (1.f + __expf(-z[0]));
                const float fg = 1.f / (1.f + __expf(-z[1]));
                const float gt = tanhf(z[2]);
                const float og = 1.f / (1.f + __expf(-z[3]));
                const float cn = fg * creg[jjj] + ig * gt;
                creg[jjj] = cn;
                const float hn = og * tanhf(cn);
                hi16[jjj] = f2bf(hn);
                lo16[jjj] = f2bf(hn - bf2f(hi16[jjj]));
            }
            // cell [tile][b], u32 half w  (j's {4t+2w, 4t+2w+1})
            const unsigned hiw = (unsigned)hi16[0] | ((unsigned)hi16[1] << 16);
            const unsigned low = (unsigned)lo16[0] | ((unsigned)lo16[1] << 16);
            const int pidx = tile * 128 + b * 2 + w;
            __hip_atomic_store(&ohi[pidx], hiw, __ATOMIC_RELAXED, __HIP_MEMORY_SCOPE_AGENT);
            __hip_atomic_store(&olo[pidx], low, __ATOMIC_RELAXED, __HIP_MEMORY_SCOPE_AGENT);
        }
        __syncthreads();   // (B) vmcnt(0): every thread's sc1 stores drained

        // ---- device-wide epoch barrier: FULLY RELAXED (no wbL2/inv) ----
        if (t < SEQ - 1) {
            if (tid == 0) {
                const unsigned epoch = (unsigned)(t + 1);
                const unsigned arr = __hip_atomic_fetch_add(&bar[0], 1u,
                                        __ATOMIC_RELAXED, __HIP_MEMORY_SCOPE_AGENT);
                if (arr == 256u * epoch - 1u) {
                    __hip_atomic_store(&bar[1], epoch,
                                       __ATOMIC_RELAXED, __HIP_MEMORY_SCOPE_AGENT);
                } else {
                    while (__hip_atomic_load(&bar[1], __ATOMIC_RELAXED,
                                             __HIP_MEMORY_SCOPE_AGENT) < epoch)
                        __builtin_amdgcn_s_sleep(8);
                }
            }
            __syncthreads();   // (C) whole block released
        }
    }
}

// ---------------------------------------------------------------------------
// Kernel 3: out[b][v] = fc_b[v] + sum_k h[b][k] * fc_W[v][k]
// h planes now [k/4][b] u64 cells (u32 idx = (k>>2)*128 + b*2 + ((k>>1)&1)).
// ---------------------------------------------------------------------------
__global__ __launch_bounds__(256) void lstm_fc(
    const unsigned* __restrict__ h_hi,
    const unsigned* __restrict__ h_lo,
    const float* __restrict__ fc_W,            // [VOCAB, H]
    const float* __restrict__ fc_b,
    float* __restrict__ out)                   // [B, VOCAB]
{
    const int v0  = blockIdx.x * 64;
    const int tid = threadIdx.x;
    const int ty  = tid >> 4;
    const int tx  = tid & 15;

    __shared__ float Hs[64][36];
    __shared__ float Ws[64][36];

    float acc[4][4];
#pragma unroll
    for (int i = 0; i < 4; ++i)
#pragma unroll
        for (int j = 0; j < 4; ++j) acc[i][j] = 0.f;

    const int lr = tid >> 2;          // b
    const int lc = (tid & 3) * 8;     // k offset in 32-chunk
    const float* wbase = fc_W + (long)(v0 + lr) * HIDDEN + lc;

    for (int k0 = 0; k0 < HIDDEN; k0 += 32) {
#pragma unroll
        for (int e = 0; e < 8; ++e) {
            const int k = k0 + lc + e;
            const int ui = (k >> 2) * 128 + lr * 2 + ((k >> 1) & 1);
            const unsigned vh = h_hi[ui];
            const unsigned vl = h_lo[ui];
            const unsigned short h16 = (k & 1) ? (unsigned short)(vh >> 16) : (unsigned short)(vh & 0xffff);
            const unsigned short l16 = (k & 1) ? (unsigned short)(vl >> 16) : (unsigned short)(vl & 0xffff);
            Hs[lr][lc + e] = bf2f(h16) + bf2f(l16);
        }
        *(float4*)&Ws[lr][lc]     = *(const float4*)(wbase + k0);
        *(float4*)&Ws[lr][lc + 4] = *(const float4*)(wbase + k0 + 4);
        __syncthreads();

#pragma unroll
        for (int kk = 0; kk < 32; kk += 4) {
            float4 hv[4], wv[4];
#pragma unroll
            for (int i = 0; i < 4; ++i) hv[i] = *(const float4*)&Hs[ty + 16 * i][kk];
#pragma unroll
            for (int j = 0; j < 4; ++j) wv[j] = *(const float4*)&Ws[tx + 16 * j][kk];
#pragma unroll
            for (int i = 0; i < 4; ++i)
#pragma unroll
                for (int j = 0; j < 4; ++j)
                    acc[i][j] += hv[i].x * wv[j].x + hv[i].y * wv[j].y
                               + hv[i].z * wv[j].z + hv[i].w * wv[j].w;
        }
        __syncthreads();
    }

#pragma unroll
    for (int j = 0; j < 4; ++j) {
        const int v = v0 + tx + 16 * j;
        const float bias = fc_b[v];
#pragma unroll
        for (int i = 0; i < 4; ++i) {
            const int b = ty + 16 * i;
            out[(long)b * VOCAB + v] = acc[i][j] + bias;
        }
    }
}

// ---------------------------------------------------------------------------
extern "C" void kernel_launch(void* const* d_in, const int* in_sizes, int n_in,
                              void* d_out, int out_size, void* d_ws, size_t ws_size,
                              hipStream_t stream)
{
    const int*   x     = (const int*)d_in[0];
    const float* emb   = (const float*)d_in[1];
    const float* W_ih  = (const float*)d_in[2];
    const float* W_hh  = (const float*)d_in[3];
    const float* b_ih  = (const float*)d_in[4];
    const float* b_hh  = (const float*)d_in[5];
    const float* fc_W  = (const float*)d_in[6];
    const float* fc_b  = (const float*)d_in[7];
    float* out = (float*)d_out;

    // ws layout: xgT f32 [T][4H][B] (268 MB) | Wf u16 (16 MB)
    //          | hAhi hAlo hBhi hBlo u32 planes (4x128 KB) | bar (2 u32)
    float* xgT = (float*)d_ws;
    unsigned short* Wf = (unsigned short*)(xgT + (long)SEQ * G4 * BATCH);
    unsigned* hAhi = (unsigned*)(Wf + (long)256 * 32 * 2 * 512);
    unsigned* hAlo = hAhi + BATCH * 512;
    unsigned* hBhi = hAlo + BATCH * 512;
    unsigned* hBlo = hBhi + BATCH * 512;
    unsigned* bar  = hBlo + BATCH * 512;

    lstm_wprep<<<dim3(256, 8), 256, 0, stream>>>(W_hh, Wf);
    lstm_xgates<<<dim3(G4 / 64, SEQ), 256, 0, stream>>>(x, emb, W_ih, b_ih, b_hh, xgT);
    lstm_init<<<dim3(BATCH * 512 / 256), 256, 0, stream>>>(hAhi, hAlo, bar);

    void* args[] = {(void*)&Wf, (void*)&xgT,
                    (void*)&hAhi, (void*)&hAlo, (void*)&hBhi, (void*)&hBlo,
                    (void*)&bar};
    hipLaunchCooperativeKernel((void*)lstm_persist, dim3(256), dim3(512),
                               args, 0, stream);

    // SEQ even -> final h in A planes
    lstm_fc<<<dim3(VOCAB / 64), 256, 0, stream>>>(hAhi, hAlo, fc_W, fc_b, out);
}